// Round 1
// baseline (381.172 us; speedup 1.0000x reference)
//
#include <hip/hip_runtime.h>

// ---------------------------------------------------------------------------
// EncoderLayer, MI355X gfx950. fp32 I/O, bf16 MFMA internally.
// r9: attn P-in-register rewrite. r8 post-mortem: attn LDS pipe was the pole
//     (28KB/wave-iter incl. the Ps LDS round-trip, 7.3M conflict cycles, 2
//     barriers/tile). The swapped-S^T layout makes P's q-row lane-local, so
//     the PV A-fragment is reachable with v_permlane32_swap + v_permlane16_swap
//     (T12 adapted to 16x16 frags) -- Ps LDS deleted, Ks/Vt double-buffered,
//     one barrier per K-tile, global prefetch 2 tiles ahead.
// MFMA 16x16x32 bf16 layouts (m89/m91 verified):
//   A: lane holds A[m=lane&15][k=quad*8+j]; B: Bt[n=lane&15][k=quad*8+j]
//   C/D: reg r -> row=quad*4+r, col=lane&15
// Workspace (MB): 0-6 wqkvT | 6-8 woT | 8-16 w1T | 16-24 w2T | 24-32 ln |
//   32-48 qkb | 48-56 vbT | 56-64 ao | 64-80 x2 | 80-96 partials hi
// ---------------------------------------------------------------------------

typedef __attribute__((ext_vector_type(8))) unsigned short u16x8;
typedef __attribute__((ext_vector_type(4))) unsigned short u16x4;
typedef __attribute__((ext_vector_type(8))) __bf16 bf16x8;
typedef __attribute__((ext_vector_type(4))) float f32x4;
typedef __attribute__((ext_vector_type(4))) unsigned int u32x4;

#define C_SCALE 0.1803368801111f   // log2(e)/8 — folded into wk/bk

static __device__ __forceinline__ unsigned short f2b(float f) {
    return __builtin_bit_cast(unsigned short, (__bf16)f);
}
static __device__ __forceinline__ float b2f(unsigned short h) {
    unsigned u = ((unsigned)h) << 16;
    float f;
    __builtin_memcpy(&f, &u, 4);
    return f;
}

static __device__ __forceinline__ void async_cp16(
    const unsigned short* g, unsigned short* l)
{
    __builtin_amdgcn_global_load_lds(
        (const __attribute__((address_space(1))) unsigned int*)g,
        (__attribute__((address_space(3))) unsigned int*)l,
        16, 0, 0);
}

// ---------------------------------------------------------------------------
// All six weight transposes (fp32 -> bf16, [R][C] -> [C][R]) in one launch.
// ---------------------------------------------------------------------------
__global__ __launch_bounds__(256) void transpose_all_k(
    const float* __restrict__ wq, const float* __restrict__ wk,
    const float* __restrict__ wv, const float* __restrict__ wo,
    const float* __restrict__ w1, const float* __restrict__ w2,
    unsigned short* __restrict__ wqkvT, unsigned short* __restrict__ woT,
    unsigned short* __restrict__ w1T, unsigned short* __restrict__ w2T)
{
    __shared__ unsigned short tile[32][33];
    const int ti = blockIdx.x;
    const float* in;
    unsigned short* out;
    int R, C, bi, bj;
    float sc = 1.0f;
    if (ti < 4096) {
        R = 1024; C = 1024;
        bi = (ti & 1023) >> 5; bj = ti & 31;
        int z = ti >> 10;
        in = (z == 0) ? wq : (z == 1) ? wk : (z == 2) ? wv : wo;
        out = (z < 3) ? wqkvT + (size_t)z * 1024 * 1024 : woT;
        if (z == 1) sc = C_SCALE;
    } else if (ti < 8192) {
        R = 1024; C = 4096;
        int l = ti - 4096;
        bi = l >> 7; bj = l & 127;
        in = w1; out = w1T;
    } else {
        R = 4096; C = 1024;
        int l = ti - 8192;
        bi = l >> 5; bj = l & 31;
        in = w2; out = w2T;
    }
    const int tx = threadIdx.x & 31, ty = threadIdx.x >> 5;
#pragma unroll
    for (int rr = 0; rr < 4; ++rr) {
        int r = ty + rr * 8;
        tile[r][tx] = f2b(in[(size_t)(bi * 32 + r) * C + bj * 32 + tx] * sc);
    }
    __syncthreads();
#pragma unroll
    for (int rr = 0; rr < 4; ++rr) {
        int r = ty + rr * 8;
        out[(size_t)(bj * 32 + r) * R + bi * 32 + tx] = tile[tx][r];
    }
}

__global__ __launch_bounds__(256) void concat3_k(
    const float* __restrict__ a, const float* __restrict__ b,
    const float* __restrict__ c, float* __restrict__ o)
{
    int t = blockIdx.x * 256 + threadIdx.x;
    float v = (t < 1024) ? a[t]
            : ((t < 2048) ? b[t - 1024] * C_SCALE : c[t - 2048]);
    o[t] = v;
}

// ---------------------------------------------------------------------------
__global__ __launch_bounds__(256) void ln_kernel(
    const float* __restrict__ x, const float* __restrict__ g,
    const float* __restrict__ be, unsigned short* __restrict__ o)
{
    const int row = blockIdx.x;
    const int t = threadIdx.x;
    const float* xr = x + (size_t)row * 1024;
    float4 v4 = *reinterpret_cast<const float4*>(&xr[t * 4]);
    float f[4] = {v4.x, v4.y, v4.z, v4.w};
    float s = f[0] + f[1] + f[2] + f[3];
    float ss = f[0] * f[0] + f[1] * f[1] + f[2] * f[2] + f[3] * f[3];
#pragma unroll
    for (int d = 1; d < 64; d <<= 1) {
        s += __shfl_xor(s, d);
        ss += __shfl_xor(ss, d);
    }
    __shared__ float sb[4], ssb[4];
    const int wave = t >> 6;
    if ((t & 63) == 0) { sb[wave] = s; ssb[wave] = ss; }
    __syncthreads();
    s = sb[0] + sb[1] + sb[2] + sb[3];
    ss = ssb[0] + ssb[1] + ssb[2] + ssb[3];
    const float mu = s * (1.0f / 1024.0f);
    const float var = ss * (1.0f / 1024.0f) - mu * mu;
    const float rs = rsqrtf(var + 1e-5f);
    u16x4 r4;
#pragma unroll
    for (int j = 0; j < 4; ++j)
        r4[j] = f2b((f[j] - mu) * rs * g[t * 4 + j] + be[t * 4 + j]);
    *reinterpret_cast<u16x4*>(&o[(size_t)row * 1024 + t * 4]) = r4;
}

// ---------------------------------------------------------------------------
// Fused: x2 = sum(4 bf16 partials) + bias + x;  ln = LayerNorm(x2; g, be)
// ---------------------------------------------------------------------------
__global__ __launch_bounds__(256) void reduce_ln_kernel(
    const unsigned short* __restrict__ pa, const unsigned short* __restrict__ pb,
    const float* __restrict__ bias, const float* __restrict__ x,
    const float* __restrict__ g, const float* __restrict__ be,
    float* __restrict__ x2, unsigned short* __restrict__ o)
{
    const int row = blockIdx.x;
    const int t = threadIdx.x;
    const size_t base = (size_t)row * 1024 + t * 4;
    float4 x4 = *reinterpret_cast<const float4*>(&x[base]);
    float4 bb = *reinterpret_cast<const float4*>(&bias[t * 4]);
    float f[4] = {x4.x + bb.x, x4.y + bb.y, x4.z + bb.z, x4.w + bb.w};
#pragma unroll
    for (int z = 0; z < 2; ++z) {
        u16x4 va = *reinterpret_cast<const u16x4*>(&pa[(size_t)z * 4096 * 1024 + base]);
        u16x4 vb = *reinterpret_cast<const u16x4*>(&pb[(size_t)z * 4096 * 1024 + base]);
#pragma unroll
        for (int j = 0; j < 4; ++j) f[j] += b2f(va[j]) + b2f(vb[j]);
    }
    *reinterpret_cast<float4*>(&x2[base]) = {f[0], f[1], f[2], f[3]};
    float s = f[0] + f[1] + f[2] + f[3];
    float ss = f[0] * f[0] + f[1] * f[1] + f[2] * f[2] + f[3] * f[3];
#pragma unroll
    for (int d = 1; d < 64; d <<= 1) {
        s += __shfl_xor(s, d);
        ss += __shfl_xor(ss, d);
    }
    __shared__ float sb[4], ssb[4];
    const int wave = t >> 6;
    if ((t & 63) == 0) { sb[wave] = s; ssb[wave] = ss; }
    __syncthreads();
    s = sb[0] + sb[1] + sb[2] + sb[3];
    ss = ssb[0] + ssb[1] + ssb[2] + ssb[3];
    const float mu = s * (1.0f / 1024.0f);
    const float var = ss * (1.0f / 1024.0f) - mu * mu;
    const float rs = rsqrtf(var + 1e-5f);
    u16x4 r4;
#pragma unroll
    for (int j = 0; j < 4; ++j)
        r4[j] = f2b((f[j] - mu) * rs * g[t * 4 + j] + be[t * 4 + j]);
    *reinterpret_cast<u16x4*>(&o[base]) = r4;
}

// ---------------------------------------------------------------------------
// Fused final: out = sum(4 bf16 partials) + bias + x2
// ---------------------------------------------------------------------------
__global__ __launch_bounds__(256) void reduce_out4_k(
    const unsigned short* __restrict__ pa, const unsigned short* __restrict__ pb,
    const float* __restrict__ bias, const float* __restrict__ x2,
    float* __restrict__ out)
{
    const size_t i4 = ((size_t)blockIdx.x * 256 + threadIdx.x) * 4;
    float4 x4 = *reinterpret_cast<const float4*>(&x2[i4]);
    float4 bb = *reinterpret_cast<const float4*>(&bias[i4 & 1023]);
    float a0 = x4.x + bb.x, a1 = x4.y + bb.y, a2 = x4.z + bb.z, a3 = x4.w + bb.w;
#pragma unroll
    for (int z = 0; z < 2; ++z) {
        u16x4 va = *reinterpret_cast<const u16x4*>(&pa[(size_t)z * 4096 * 1024 + i4]);
        u16x4 vb = *reinterpret_cast<const u16x4*>(&pb[(size_t)z * 4096 * 1024 + i4]);
        a0 += b2f(va[0]) + b2f(vb[0]);
        a1 += b2f(va[1]) + b2f(vb[1]);
        a2 += b2f(va[2]) + b2f(vb[2]);
        a3 += b2f(va[3]) + b2f(vb[3]);
    }
    *reinterpret_cast<float4*>(&out[i4]) = {a0, a1, a2, a3};
}

// ---------------------------------------------------------------------------
// GEMM: C[M][.] = A[M][lda] @ Bt[.][ldb]^T (+bias)(+ReLU)
// BM=128, BN=128, BK=32, m97 global_load_lds staging. z-split over K.
// MODE 0: bf16 row-major; 2: fused QKV epilogue (gc<2048 -> qkb; else V^T);
//      5: bf16 partial slice (z<2 -> Cv + z*4096*N; else Cv2 + (z-2)*4096*N)
// ---------------------------------------------------------------------------
template<int MODE, int RELU>
__global__ __launch_bounds__(256, 4) void gemm_bt(
    const unsigned short* __restrict__ A, int lda,
    const unsigned short* __restrict__ Bt, int ldb,
    const float* __restrict__ bias,
    void* __restrict__ Cv, void* __restrict__ Cv2, int N, int Kloop)
{
    __shared__ unsigned short As[128 * 32];
    __shared__ unsigned short Bs[128 * 32];
    const int t = threadIdx.x;
    const int wave = t >> 6, lane = t & 63;
    const int quad = lane >> 4, l16 = lane & 15;
    const int wm = wave >> 1, wn = wave & 1;
    const int m0 = blockIdx.y * 128;
    const int n0 = blockIdx.x * 128;
    const int k0 = blockIdx.z * Kloop;
    const int rl = lane >> 2;
    const int cl = (lane & 3) * 8;

    f32x4 acc[4][4];
#pragma unroll
    for (int mi = 0; mi < 4; ++mi)
#pragma unroll
        for (int ni = 0; ni < 4; ++ni) acc[mi][ni] = {0.f, 0.f, 0.f, 0.f};

    for (int kt = 0; kt < Kloop; kt += 32) {
#pragma unroll
        for (int j = 0; j < 4; ++j) {
            int c = wave * 4 + j;
            if (c < 8) {
                async_cp16(&A[(size_t)(m0 + c * 16 + rl) * lda + k0 + kt + cl],
                           &As[c * 512 + lane * 8]);
            } else {
                int bc = c - 8;
                async_cp16(&Bt[(size_t)(n0 + bc * 16 + rl) * ldb + k0 + kt + cl],
                           &Bs[bc * 512 + lane * 8]);
            }
        }
        __syncthreads();
        bf16x8 af[4], bfr[4];
#pragma unroll
        for (int mi = 0; mi < 4; ++mi)
            af[mi] = __builtin_bit_cast(bf16x8,
                *reinterpret_cast<const u16x8*>(&As[(wm * 64 + mi * 16 + l16) * 32 + quad * 8]));
#pragma unroll
        for (int ni = 0; ni < 4; ++ni)
            bfr[ni] = __builtin_bit_cast(bf16x8,
                *reinterpret_cast<const u16x8*>(&Bs[(wn * 64 + ni * 16 + l16) * 32 + quad * 8]));
#pragma unroll
        for (int mi = 0; mi < 4; ++mi)
#pragma unroll
            for (int ni = 0; ni < 4; ++ni)
                acc[mi][ni] = __builtin_amdgcn_mfma_f32_16x16x32_bf16(
                    af[mi], bfr[ni], acc[mi][ni], 0, 0, 0);
        __syncthreads();
    }

#pragma unroll
    for (int mi = 0; mi < 4; ++mi) {
        const int gr0 = m0 + wm * 64 + mi * 16 + quad * 4;
#pragma unroll
        for (int ni = 0; ni < 4; ++ni) {
            const int gc = n0 + wn * 64 + ni * 16 + l16;
            if (MODE == 2) {
                const float bv = bias[gc];
                if (gc < 2048) {
#pragma unroll
                    for (int r = 0; r < 4; ++r)
                        ((unsigned short*)Cv)[(size_t)(gr0 + r) * 2048 + gc] =
                            f2b(acc[mi][ni][r] + bv);
                } else {
                    u16x4 pk;
#pragma unroll
                    for (int r = 0; r < 4; ++r) pk[r] = f2b(acc[mi][ni][r] + bv);
                    const int b = gr0 >> 11, s0 = gr0 & 2047;
                    *reinterpret_cast<u16x4*>(
                        &((unsigned short*)Cv2)[((size_t)b * 1024 + (gc - 2048)) * 2048 + s0]) = pk;
                }
            } else if (MODE == 5) {
                unsigned short* base = (blockIdx.z < 2)
                    ? (unsigned short*)Cv  + (size_t)blockIdx.z * 4096 * N
                    : (unsigned short*)Cv2 + (size_t)(blockIdx.z - 2) * 4096 * N;
#pragma unroll
                for (int r = 0; r < 4; ++r)
                    base[(size_t)(gr0 + r) * N + gc] = f2b(acc[mi][ni][r]);
            } else {
                const float bv = bias[gc];
#pragma unroll
                for (int r = 0; r < 4; ++r) {
                    float v = acc[mi][ni][r] + bv;
                    if (RELU) v = fmaxf(v, 0.f);
                    ((unsigned short*)Cv)[(size_t)(gr0 + r) * N + gc] = f2b(v);
                }
            }
        }
    }
}

// ---------------------------------------------------------------------------
// Flash attention, r9. K pre-scaled by log2(e)/8 -> p = exp2(s).
// qkb: [4096][2048] (Q 0..1023, K' 1024..2047, head h at h*64).
// vbT: [2][1024][2048]. Grid (16, 32): 128 q/block, 4 waves x 32 q.
// S computed TRANSPOSED via mfma(A=K, B=Q): lane (quad,l16) reg r holds
// p[key=16kf+4quad+r][q=l16(+16m)]. The PV A-fragment (lane needs keys
// 8quad+j at the same q) is built IN-REGISTER:
//   d0=pk(r0,r1), d1=pk(r2,r3) per kf;  for the kf pair (2kh, 2kh+1):
//   (W0,W2)=permlane16_swap(permlane32_swap(d0_even, d0_odd)), same for d1
//   -> {W0,W1,W2,W3} is the bf16x8 A-frag. No Ps LDS round-trip.
// Ks/Vt double-buffered -> ONE barrier per K-tile; global prefetch 2 ahead.
// l computed by MFMA against a ones fragment (C-layout matches o_acc rows).
// ---------------------------------------------------------------------------
__global__ __launch_bounds__(256, 2) void attn_kernel(
    const unsigned short* __restrict__ qkb, const unsigned short* __restrict__ vbT,
    unsigned short* __restrict__ ao)
{
    __shared__ unsigned short Ks[2][64][72];   // [buf][key][d]
    __shared__ unsigned short Vt[2][64][72];   // [buf][dv][key]
    const int t = threadIdx.x;
    const int lane = t & 63;
    const int quad = lane >> 4, l16 = lane & 15;
    const int wave = t >> 6;
    const int bh = blockIdx.y;
    const int b = bh >> 4, h = bh & 15;
    const int q0 = blockIdx.x * 128 + wave * 32;
    const size_t qk_base = (size_t)b * 2048 * 2048;
    const size_t vt_base = (size_t)b * 1024 * 2048 + (size_t)h * 64 * 2048;

    // Q as B-operand: lane holds Q[q=l16 (+16m)][d=quad*8+j (+32kk)]
    bf16x8 qf[2][2];
#pragma unroll
    for (int m = 0; m < 2; ++m)
#pragma unroll
        for (int kk = 0; kk < 2; ++kk)
            qf[m][kk] = __builtin_bit_cast(bf16x8, *reinterpret_cast<const u16x8*>(
                &qkb[qk_base + (size_t)(q0 + m * 16 + l16) * 2048 + h * 64 + kk * 32 + quad * 8]));

    // ones fragment (bf16 1.0 = 0x3F80) for l = P @ 1
    u16x8 ones_u;
#pragma unroll
    for (int j = 0; j < 8; ++j) ones_u[j] = 0x3F80;
    const bf16x8 onesf = __builtin_bit_cast(bf16x8, ones_u);

    f32x4 o_acc[2][4], l_frag[2];
#pragma unroll
    for (int m = 0; m < 2; ++m) {
        l_frag[m] = {0.f, 0.f, 0.f, 0.f};
#pragma unroll
        for (int nf = 0; nf < 4; ++nf) o_acc[m][nf] = {0.f, 0.f, 0.f, 0.f};
    }

    const int srow0 = t >> 3, sc8 = (t & 7) * 8;   // 32 rows x 8 cols per wave set
    const int srow1 = srow0 + 32;

    const unsigned short* kg0 = &qkb[qk_base + (size_t)srow0 * 2048 + 1024 + h * 64 + sc8];
    const unsigned short* kg1 = kg0 + (size_t)32 * 2048;
    const unsigned short* vg0 = &vbT[vt_base + (size_t)srow0 * 2048 + sc8];
    const unsigned short* vg1 = vg0 + (size_t)32 * 2048;

    u16x8 kr[2], vr[2];
    // tile 0 -> buf 0
    kr[0] = *reinterpret_cast<const u16x8*>(kg0);
    kr[1] = *reinterpret_cast<const u16x8*>(kg1);
    vr[0] = *reinterpret_cast<const u16x8*>(vg0);
    vr[1] = *reinterpret_cast<const u16x8*>(vg1);
    *reinterpret_cast<u16x8*>(&Ks[0][srow0][sc8]) = kr[0];
    *reinterpret_cast<u16x8*>(&Ks[0][srow1][sc8]) = kr[1];
    *reinterpret_cast<u16x8*>(&Vt[0][srow0][sc8]) = vr[0];
    *reinterpret_cast<u16x8*>(&Vt[0][srow1][sc8]) = vr[1];
    // tile 1 -> regs
    kr[0] = *reinterpret_cast<const u16x8*>(kg0 + (size_t)64 * 2048);
    kr[1] = *reinterpret_cast<const u16x8*>(kg1 + (size_t)64 * 2048);
    vr[0] = *reinterpret_cast<const u16x8*>(vg0 + 64);
    vr[1] = *reinterpret_cast<const u16x8*>(vg1 + 64);
    __syncthreads();

    for (int it = 0; it < 32; ++it) {
        const int cur = it & 1, nxt = cur ^ 1;
        // stage tile it+1 into the other buffer (reads of it were fenced by
        // the barrier at the end of iter it-1)
        if (it + 1 < 32) {
            *reinterpret_cast<u16x8*>(&Ks[nxt][srow0][sc8]) = kr[0];
            *reinterpret_cast<u16x8*>(&Ks[nxt][srow1][sc8]) = kr[1];
            *reinterpret_cast<u16x8*>(&Vt[nxt][srow0][sc8]) = vr[0];
            *reinterpret_cast<u16x8*>(&Vt[nxt][srow1][sc8]) = vr[1];
        }
        // prefetch tile it+2 from global (latency hidden under this iter)
        if (it + 2 < 32) {
            const size_t ko = (size_t)(it + 2) * 64 * 2048;
            const int vo = (it + 2) * 64;
            kr[0] = *reinterpret_cast<const u16x8*>(kg0 + ko);
            kr[1] = *reinterpret_cast<const u16x8*>(kg1 + ko);
            vr[0] = *reinterpret_cast<const u16x8*>(vg0 + vo);
            vr[1] = *reinterpret_cast<const u16x8*>(vg1 + vo);
        }

#pragma unroll
        for (int kh = 0; kh < 2; ++kh) {
            // S^T for the two 16-key fragments of this 32-key half
            unsigned d0[2][2], d1[2][2];   // [m][kfi]
#pragma unroll
            for (int kfi = 0; kfi < 2; ++kfi) {
                const int kf = kh * 2 + kfi;
                bf16x8 kfr0 = __builtin_bit_cast(bf16x8,
                    *reinterpret_cast<const u16x8*>(&Ks[cur][kf * 16 + l16][quad * 8]));
                bf16x8 kfr1 = __builtin_bit_cast(bf16x8,
                    *reinterpret_cast<const u16x8*>(&Ks[cur][kf * 16 + l16][32 + quad * 8]));
#pragma unroll
                for (int m = 0; m < 2; ++m) {
                    f32x4 s = {0.f, 0.f, 0.f, 0.f};
                    s = __builtin_amdgcn_mfma_f32_16x16x32_bf16(kfr0, qf[m][0], s, 0, 0, 0);
                    s = __builtin_amdgcn_mfma_f32_16x16x32_bf16(kfr1, qf[m][1], s, 0, 0, 0);
                    d0[m][kfi] = (unsigned)f2b(exp2f(s[0])) |
                                 ((unsigned)f2b(exp2f(s[1])) << 16);
                    d1[m][kfi] = (unsigned)f2b(exp2f(s[2])) |
                                 ((unsigned)f2b(exp2f(s[3])) << 16);
                }
            }
            // in-register transpose to PV A-frags: lane keeps its q (=l16),
            // keys redistributed across quads via the two swap ops.
            bf16x8 pfr[2];
#pragma unroll
            for (int m = 0; m < 2; ++m) {
                unsigned x0 = d0[m][0], y0 = d0[m][1];
                unsigned x1 = d1[m][0], y1 = d1[m][1];
                asm("v_permlane32_swap_b32 %0, %1\n\t"
                    "v_permlane16_swap_b32 %0, %1"
                    : "+v"(x0), "+v"(y0));
                asm("v_permlane32_swap_b32 %0, %1\n\t"
                    "v_permlane16_swap_b32 %0, %1"
                    : "+v"(x1), "+v"(y1));
                u32x4 pw = {x0, x1, y0, y1};   // W0,W1,W2,W3
                pfr[m] = __builtin_bit_cast(bf16x8, pw);
                l_frag[m] = __builtin_amdgcn_mfma_f32_16x16x32_bf16(
                    pfr[m], onesf, l_frag[m], 0, 0, 0);
            }
#pragma unroll
            for (int nf = 0; nf < 4; ++nf) {
                bf16x8 vfr = __builtin_bit_cast(bf16x8,
                    *reinterpret_cast<const u16x8*>(&Vt[cur][nf * 16 + l16][kh * 32 + quad * 8]));
#pragma unroll
                for (int m = 0; m < 2; ++m)
                    o_acc[m][nf] = __builtin_amdgcn_mfma_f32_16x16x32_bf16(
                        pfr[m], vfr, o_acc[m][nf], 0, 0, 0);
            }
        }
        __syncthreads();
    }

    // store: o_acc rows q = q0 + m*16 + quad*4 + r; l_frag rows align.
#pragma unroll
    for (int m = 0; m < 2; ++m) {
#pragma unroll
        for (int r = 0; r < 4; ++r) {
            const float inv = 1.0f / l_frag[m][r];
            const int row = q0 + m * 16 + quad * 4 + r;
#pragma unroll
            for (int nf = 0; nf < 4; ++nf)
                ao[(size_t)b * 2048 * 1024 + (size_t)row * 1024 + h * 64 + nf * 16 + l16] =
                    f2b(o_acc[m][nf][r] * inv);
        }
    }
}

// ---------------------------------------------------------------------------
extern "C" void kernel_launch(void* const* d_in, const int* in_sizes, int n_in,
                              void* d_out, int out_size, void* d_ws, size_t ws_size,
                              hipStream_t stream)
{
    const float* x   = (const float*)d_in[0];
    const float* wq  = (const float*)d_in[1];
    const float* bq  = (const float*)d_in[2];
    const float* wk  = (const float*)d_in[3];
    const float* bk  = (const float*)d_in[4];
    const float* wv  = (const float*)d_in[5];
    const float* bv  = (const float*)d_in[6];
    const float* wo  = (const float*)d_in[7];
    const float* bo  = (const float*)d_in[8];
    const float* w1  = (const float*)d_in[9];
    const float* b1  = (const float*)d_in[10];
    const float* w2  = (const float*)d_in[11];
    const float* b2  = (const float*)d_in[12];
    const float* g1  = (const float*)d_in[13];
    const float* be1 = (const float*)d_in[14];
    const float* g2  = (const float*)d_in[15];
    const float* be2 = (const float*)d_in[16];
    float* out = (float*)d_out;
    char*  ws  = (char*)d_ws;

    const int M = 4096, D = 1024, DFF = 4096;
    const size_t MB = 1 << 20;

    unsigned short* wqkvT = (unsigned short*)(ws + 0 * MB);   // [3072][1024] 6MB
    unsigned short* woT   = (unsigned short*)(ws + 6 * MB);   // 2MB
    unsigned short* w1T   = (unsigned short*)(ws + 8 * MB);   // 8MB
    unsigned short* w2T   = (unsigned short*)(ws + 16 * MB);  // 8MB
    unsigned short* ln    = (unsigned short*)(ws + 24 * MB);  // 8MB
    unsigned short* qkb   = (unsigned short*)(ws + 32 * MB);  // 16MB
    unsigned short* vbT   = (unsigned short*)(ws + 48 * MB);  // 8MB
    unsigned short* ao    = (unsigned short*)(ws + 56 * MB);  // 8MB
    unsigned short* ff1   = (unsigned short*)(ws + 32 * MB);  // 32MB (reuse)
    float*          x2    = (float*)(ws + 64 * MB);           // 16MB
    float*          bqkv  = (float*)(ws + 80 * MB);           // 12KB (pre-partials)
    unsigned short* pHi   = (unsigned short*)(ws + 80 * MB);  // slices 0,1 (16MB)
    unsigned short* pOlo  = (unsigned short*)(ws + 32 * MB);  // O-proj slices 2,3
    unsigned short* pFlo  = (unsigned short*)(ws + 0 * MB);   // FF2 slices 2,3

    // --- weight prep + LN1 ---
    transpose_all_k<<<12288, 256, 0, stream>>>(wq, wk, wv, wo, w1, w2,
                                               wqkvT, woT, w1T, w2T);
    concat3_k<<<12, 256, 0, stream>>>(bq, bk, bv, bqkv);
    ln_kernel<<<M, 256, 0, stream>>>(x, g1, be1, ln);
    // --- fused QKV projection: QK' -> qkb, V -> vbT (V^T) ---
    gemm_bt<2, 0><<<dim3(24, 32), 256, 0, stream>>>(
        ln, D, wqkvT, D, bqkv, qkb, vbT, 3072, D);
    // --- attention ---
    attn_kernel<<<dim3(16, 32), 256, 0, stream>>>(qkb, vbT, ao);
    // --- O projection split-K4 bf16 partials; reduce + residual + LN2 ---
    gemm_bt<5, 0><<<dim3(8, 32, 4), 256, 0, stream>>>(
        ao, D, woT, D, nullptr, pHi, pOlo, 1024, 256);
    reduce_ln_kernel<<<M, 256, 0, stream>>>(pHi, pOlo, bo, x, g2, be2, x2, ln);
    // --- FFN ---
    gemm_bt<0, 1><<<dim3(32, 32), 256, 0, stream>>>(
        ln, D, w1T, D, b1, ff1, nullptr, DFF, D);
    gemm_bt<5, 0><<<dim3(8, 32, 4), 256, 0, stream>>>(
        ff1, DFF, w2T, DFF, nullptr, pHi, pFlo, 1024, 1024);
    reduce_out4_k<<<4096, 256, 0, stream>>>(pHi, pFlo, b2, x2, out);
}

// Round 2
// 378.945 us; speedup vs baseline: 1.0059x; 1.0059x over previous
//
#include <hip/hip_runtime.h>

// ---------------------------------------------------------------------------
// EncoderLayer, MI355X gfx950. fp32 I/O, bf16 MFMA internally.
// r10: attn occupancy fix. r9 post-mortem: removing the Ps LDS round-trip and
//     halving barriers changed nothing (75us) -> kernel is latency-bound at
//     2 blocks/CU (grid 512 was the cap, not resources). r10: 64 q/block,
//     grid (32,32)=1024 blocks, 16 q/wave -> 4 blocks/CU co-resident
//     (4x36KB LDS = 144KB), 16 waves/CU = 2x latency hiding, 4 independent
//     barrier groups per CU. + T5 setprio around PV MFMA cluster.
// MFMA 16x16x32 bf16 layouts (m89/m91 verified):
//   A: lane holds A[m=lane&15][k=quad*8+j]; B: Bt[n=lane&15][k=quad*8+j]
//   C/D: reg r -> row=quad*4+r, col=lane&15
// Workspace (MB): 0-6 wqkvT | 6-8 woT | 8-16 w1T | 16-24 w2T | 24-32 ln |
//   32-48 qkb | 48-56 vbT | 56-64 ao | 64-80 x2 | 80-96 partials hi
// ---------------------------------------------------------------------------

typedef __attribute__((ext_vector_type(8))) unsigned short u16x8;
typedef __attribute__((ext_vector_type(4))) unsigned short u16x4;
typedef __attribute__((ext_vector_type(8))) __bf16 bf16x8;
typedef __attribute__((ext_vector_type(4))) float f32x4;
typedef __attribute__((ext_vector_type(4))) unsigned int u32x4;

#define C_SCALE 0.1803368801111f   // log2(e)/8 — folded into wk/bk

static __device__ __forceinline__ unsigned short f2b(float f) {
    return __builtin_bit_cast(unsigned short, (__bf16)f);
}
static __device__ __forceinline__ float b2f(unsigned short h) {
    unsigned u = ((unsigned)h) << 16;
    float f;
    __builtin_memcpy(&f, &u, 4);
    return f;
}

static __device__ __forceinline__ void async_cp16(
    const unsigned short* g, unsigned short* l)
{
    __builtin_amdgcn_global_load_lds(
        (const __attribute__((address_space(1))) unsigned int*)g,
        (__attribute__((address_space(3))) unsigned int*)l,
        16, 0, 0);
}

// ---------------------------------------------------------------------------
// All six weight transposes (fp32 -> bf16, [R][C] -> [C][R]) in one launch.
// ---------------------------------------------------------------------------
__global__ __launch_bounds__(256) void transpose_all_k(
    const float* __restrict__ wq, const float* __restrict__ wk,
    const float* __restrict__ wv, const float* __restrict__ wo,
    const float* __restrict__ w1, const float* __restrict__ w2,
    unsigned short* __restrict__ wqkvT, unsigned short* __restrict__ woT,
    unsigned short* __restrict__ w1T, unsigned short* __restrict__ w2T)
{
    __shared__ unsigned short tile[32][33];
    const int ti = blockIdx.x;
    const float* in;
    unsigned short* out;
    int R, C, bi, bj;
    float sc = 1.0f;
    if (ti < 4096) {
        R = 1024; C = 1024;
        bi = (ti & 1023) >> 5; bj = ti & 31;
        int z = ti >> 10;
        in = (z == 0) ? wq : (z == 1) ? wk : (z == 2) ? wv : wo;
        out = (z < 3) ? wqkvT + (size_t)z * 1024 * 1024 : woT;
        if (z == 1) sc = C_SCALE;
    } else if (ti < 8192) {
        R = 1024; C = 4096;
        int l = ti - 4096;
        bi = l >> 7; bj = l & 127;
        in = w1; out = w1T;
    } else {
        R = 4096; C = 1024;
        int l = ti - 8192;
        bi = l >> 5; bj = l & 31;
        in = w2; out = w2T;
    }
    const int tx = threadIdx.x & 31, ty = threadIdx.x >> 5;
#pragma unroll
    for (int rr = 0; rr < 4; ++rr) {
        int r = ty + rr * 8;
        tile[r][tx] = f2b(in[(size_t)(bi * 32 + r) * C + bj * 32 + tx] * sc);
    }
    __syncthreads();
#pragma unroll
    for (int rr = 0; rr < 4; ++rr) {
        int r = ty + rr * 8;
        out[(size_t)(bj * 32 + r) * R + bi * 32 + tx] = tile[tx][r];
    }
}

__global__ __launch_bounds__(256) void concat3_k(
    const float* __restrict__ a, const float* __restrict__ b,
    const float* __restrict__ c, float* __restrict__ o)
{
    int t = blockIdx.x * 256 + threadIdx.x;
    float v = (t < 1024) ? a[t]
            : ((t < 2048) ? b[t - 1024] * C_SCALE : c[t - 2048]);
    o[t] = v;
}

// ---------------------------------------------------------------------------
__global__ __launch_bounds__(256) void ln_kernel(
    const float* __restrict__ x, const float* __restrict__ g,
    const float* __restrict__ be, unsigned short* __restrict__ o)
{
    const int row = blockIdx.x;
    const int t = threadIdx.x;
    const float* xr = x + (size_t)row * 1024;
    float4 v4 = *reinterpret_cast<const float4*>(&xr[t * 4]);
    float f[4] = {v4.x, v4.y, v4.z, v4.w};
    float s = f[0] + f[1] + f[2] + f[3];
    float ss = f[0] * f[0] + f[1] * f[1] + f[2] * f[2] + f[3] * f[3];
#pragma unroll
    for (int d = 1; d < 64; d <<= 1) {
        s += __shfl_xor(s, d);
        ss += __shfl_xor(ss, d);
    }
    __shared__ float sb[4], ssb[4];
    const int wave = t >> 6;
    if ((t & 63) == 0) { sb[wave] = s; ssb[wave] = ss; }
    __syncthreads();
    s = sb[0] + sb[1] + sb[2] + sb[3];
    ss = ssb[0] + ssb[1] + ssb[2] + ssb[3];
    const float mu = s * (1.0f / 1024.0f);
    const float var = ss * (1.0f / 1024.0f) - mu * mu;
    const float rs = rsqrtf(var + 1e-5f);
    u16x4 r4;
#pragma unroll
    for (int j = 0; j < 4; ++j)
        r4[j] = f2b((f[j] - mu) * rs * g[t * 4 + j] + be[t * 4 + j]);
    *reinterpret_cast<u16x4*>(&o[(size_t)row * 1024 + t * 4]) = r4;
}

// ---------------------------------------------------------------------------
// Fused: x2 = sum(4 bf16 partials) + bias + x;  ln = LayerNorm(x2; g, be)
// ---------------------------------------------------------------------------
__global__ __launch_bounds__(256) void reduce_ln_kernel(
    const unsigned short* __restrict__ pa, const unsigned short* __restrict__ pb,
    const float* __restrict__ bias, const float* __restrict__ x,
    const float* __restrict__ g, const float* __restrict__ be,
    float* __restrict__ x2, unsigned short* __restrict__ o)
{
    const int row = blockIdx.x;
    const int t = threadIdx.x;
    const size_t base = (size_t)row * 1024 + t * 4;
    float4 x4 = *reinterpret_cast<const float4*>(&x[base]);
    float4 bb = *reinterpret_cast<const float4*>(&bias[t * 4]);
    float f[4] = {x4.x + bb.x, x4.y + bb.y, x4.z + bb.z, x4.w + bb.w};
#pragma unroll
    for (int z = 0; z < 2; ++z) {
        u16x4 va = *reinterpret_cast<const u16x4*>(&pa[(size_t)z * 4096 * 1024 + base]);
        u16x4 vb = *reinterpret_cast<const u16x4*>(&pb[(size_t)z * 4096 * 1024 + base]);
#pragma unroll
        for (int j = 0; j < 4; ++j) f[j] += b2f(va[j]) + b2f(vb[j]);
    }
    *reinterpret_cast<float4*>(&x2[base]) = {f[0], f[1], f[2], f[3]};
    float s = f[0] + f[1] + f[2] + f[3];
    float ss = f[0] * f[0] + f[1] * f[1] + f[2] * f[2] + f[3] * f[3];
#pragma unroll
    for (int d = 1; d < 64; d <<= 1) {
        s += __shfl_xor(s, d);
        ss += __shfl_xor(ss, d);
    }
    __shared__ float sb[4], ssb[4];
    const int wave = t >> 6;
    if ((t & 63) == 0) { sb[wave] = s; ssb[wave] = ss; }
    __syncthreads();
    s = sb[0] + sb[1] + sb[2] + sb[3];
    ss = ssb[0] + ssb[1] + ssb[2] + ssb[3];
    const float mu = s * (1.0f / 1024.0f);
    const float var = ss * (1.0f / 1024.0f) - mu * mu;
    const float rs = rsqrtf(var + 1e-5f);
    u16x4 r4;
#pragma unroll
    for (int j = 0; j < 4; ++j)
        r4[j] = f2b((f[j] - mu) * rs * g[t * 4 + j] + be[t * 4 + j]);
    *reinterpret_cast<u16x4*>(&o[base]) = r4;
}

// ---------------------------------------------------------------------------
// Fused final: out = sum(4 bf16 partials) + bias + x2
// ---------------------------------------------------------------------------
__global__ __launch_bounds__(256) void reduce_out4_k(
    const unsigned short* __restrict__ pa, const unsigned short* __restrict__ pb,
    const float* __restrict__ bias, const float* __restrict__ x2,
    float* __restrict__ out)
{
    const size_t i4 = ((size_t)blockIdx.x * 256 + threadIdx.x) * 4;
    float4 x4 = *reinterpret_cast<const float4*>(&x2[i4]);
    float4 bb = *reinterpret_cast<const float4*>(&bias[i4 & 1023]);
    float a0 = x4.x + bb.x, a1 = x4.y + bb.y, a2 = x4.z + bb.z, a3 = x4.w + bb.w;
#pragma unroll
    for (int z = 0; z < 2; ++z) {
        u16x4 va = *reinterpret_cast<const u16x4*>(&pa[(size_t)z * 4096 * 1024 + i4]);
        u16x4 vb = *reinterpret_cast<const u16x4*>(&pb[(size_t)z * 4096 * 1024 + i4]);
        a0 += b2f(va[0]) + b2f(vb[0]);
        a1 += b2f(va[1]) + b2f(vb[1]);
        a2 += b2f(va[2]) + b2f(vb[2]);
        a3 += b2f(va[3]) + b2f(vb[3]);
    }
    *reinterpret_cast<float4*>(&out[i4]) = {a0, a1, a2, a3};
}

// ---------------------------------------------------------------------------
// GEMM: C[M][.] = A[M][lda] @ Bt[.][ldb]^T (+bias)(+ReLU)
// BM=128, BN=128, BK=32, m97 global_load_lds staging. z-split over K.
// MODE 0: bf16 row-major; 2: fused QKV epilogue (gc<2048 -> qkb; else V^T);
//      5: bf16 partial slice (z<2 -> Cv + z*4096*N; else Cv2 + (z-2)*4096*N)
// ---------------------------------------------------------------------------
template<int MODE, int RELU>
__global__ __launch_bounds__(256, 4) void gemm_bt(
    const unsigned short* __restrict__ A, int lda,
    const unsigned short* __restrict__ Bt, int ldb,
    const float* __restrict__ bias,
    void* __restrict__ Cv, void* __restrict__ Cv2, int N, int Kloop)
{
    __shared__ unsigned short As[128 * 32];
    __shared__ unsigned short Bs[128 * 32];
    const int t = threadIdx.x;
    const int wave = t >> 6, lane = t & 63;
    const int quad = lane >> 4, l16 = lane & 15;
    const int wm = wave >> 1, wn = wave & 1;
    const int m0 = blockIdx.y * 128;
    const int n0 = blockIdx.x * 128;
    const int k0 = blockIdx.z * Kloop;
    const int rl = lane >> 2;
    const int cl = (lane & 3) * 8;

    f32x4 acc[4][4];
#pragma unroll
    for (int mi = 0; mi < 4; ++mi)
#pragma unroll
        for (int ni = 0; ni < 4; ++ni) acc[mi][ni] = {0.f, 0.f, 0.f, 0.f};

    for (int kt = 0; kt < Kloop; kt += 32) {
#pragma unroll
        for (int j = 0; j < 4; ++j) {
            int c = wave * 4 + j;
            if (c < 8) {
                async_cp16(&A[(size_t)(m0 + c * 16 + rl) * lda + k0 + kt + cl],
                           &As[c * 512 + lane * 8]);
            } else {
                int bc = c - 8;
                async_cp16(&Bt[(size_t)(n0 + bc * 16 + rl) * ldb + k0 + kt + cl],
                           &Bs[bc * 512 + lane * 8]);
            }
        }
        __syncthreads();
        bf16x8 af[4], bfr[4];
#pragma unroll
        for (int mi = 0; mi < 4; ++mi)
            af[mi] = __builtin_bit_cast(bf16x8,
                *reinterpret_cast<const u16x8*>(&As[(wm * 64 + mi * 16 + l16) * 32 + quad * 8]));
#pragma unroll
        for (int ni = 0; ni < 4; ++ni)
            bfr[ni] = __builtin_bit_cast(bf16x8,
                *reinterpret_cast<const u16x8*>(&Bs[(wn * 64 + ni * 16 + l16) * 32 + quad * 8]));
#pragma unroll
        for (int mi = 0; mi < 4; ++mi)
#pragma unroll
            for (int ni = 0; ni < 4; ++ni)
                acc[mi][ni] = __builtin_amdgcn_mfma_f32_16x16x32_bf16(
                    af[mi], bfr[ni], acc[mi][ni], 0, 0, 0);
        __syncthreads();
    }

#pragma unroll
    for (int mi = 0; mi < 4; ++mi) {
        const int gr0 = m0 + wm * 64 + mi * 16 + quad * 4;
#pragma unroll
        for (int ni = 0; ni < 4; ++ni) {
            const int gc = n0 + wn * 64 + ni * 16 + l16;
            if (MODE == 2) {
                const float bv = bias[gc];
                if (gc < 2048) {
#pragma unroll
                    for (int r = 0; r < 4; ++r)
                        ((unsigned short*)Cv)[(size_t)(gr0 + r) * 2048 + gc] =
                            f2b(acc[mi][ni][r] + bv);
                } else {
                    u16x4 pk;
#pragma unroll
                    for (int r = 0; r < 4; ++r) pk[r] = f2b(acc[mi][ni][r] + bv);
                    const int b = gr0 >> 11, s0 = gr0 & 2047;
                    *reinterpret_cast<u16x4*>(
                        &((unsigned short*)Cv2)[((size_t)b * 1024 + (gc - 2048)) * 2048 + s0]) = pk;
                }
            } else if (MODE == 5) {
                unsigned short* base = (blockIdx.z < 2)
                    ? (unsigned short*)Cv  + (size_t)blockIdx.z * 4096 * N
                    : (unsigned short*)Cv2 + (size_t)(blockIdx.z - 2) * 4096 * N;
#pragma unroll
                for (int r = 0; r < 4; ++r)
                    base[(size_t)(gr0 + r) * N + gc] = f2b(acc[mi][ni][r]);
            } else {
                const float bv = bias[gc];
#pragma unroll
                for (int r = 0; r < 4; ++r) {
                    float v = acc[mi][ni][r] + bv;
                    if (RELU) v = fmaxf(v, 0.f);
                    ((unsigned short*)Cv)[(size_t)(gr0 + r) * N + gc] = f2b(v);
                }
            }
        }
    }
}

// ---------------------------------------------------------------------------
// Flash attention, r10. K pre-scaled by log2(e)/8 -> p = exp2(s).
// qkb: [4096][2048] (Q 0..1023, K' 1024..2047, head h at h*64).
// vbT: [2][1024][2048]. Grid (32, 32): 64 q/block, 4 waves x 16 q.
// 4 blocks/CU (4x36KB LDS=144KB) -> 16 waves/CU, 2x r9's latency hiding.
// S computed TRANSPOSED via mfma(A=K, B=Q): lane (quad,l16) reg r holds
// p[key=16kf+4quad+r][q=l16]. PV A-fragment built IN-REGISTER via
// v_permlane32_swap + v_permlane16_swap (no Ps LDS round-trip).
// Ks/Vt double-buffered -> ONE barrier per K-tile; global prefetch 2 ahead.
// l computed by MFMA against a ones fragment (C-layout matches o_acc rows).
// ---------------------------------------------------------------------------
__global__ __launch_bounds__(256, 4) void attn_kernel(
    const unsigned short* __restrict__ qkb, const unsigned short* __restrict__ vbT,
    unsigned short* __restrict__ ao)
{
    __shared__ unsigned short Ks[2][64][72];   // [buf][key][d]
    __shared__ unsigned short Vt[2][64][72];   // [buf][dv][key]
    const int t = threadIdx.x;
    const int lane = t & 63;
    const int quad = lane >> 4, l16 = lane & 15;
    const int wave = t >> 6;
    const int bh = blockIdx.y;
    const int b = bh >> 4, h = bh & 15;
    const int q0 = blockIdx.x * 64 + wave * 16;
    const size_t qk_base = (size_t)b * 2048 * 2048;
    const size_t vt_base = (size_t)b * 1024 * 2048 + (size_t)h * 64 * 2048;

    // Q as B-operand: lane holds Q[q=l16][d=quad*8+j (+32kk)]
    bf16x8 qf[2];
#pragma unroll
    for (int kk = 0; kk < 2; ++kk)
        qf[kk] = __builtin_bit_cast(bf16x8, *reinterpret_cast<const u16x8*>(
            &qkb[qk_base + (size_t)(q0 + l16) * 2048 + h * 64 + kk * 32 + quad * 8]));

    // ones fragment (bf16 1.0 = 0x3F80) for l = P @ 1
    u16x8 ones_u;
#pragma unroll
    for (int j = 0; j < 8; ++j) ones_u[j] = 0x3F80;
    const bf16x8 onesf = __builtin_bit_cast(bf16x8, ones_u);

    f32x4 o_acc[4], l_frag;
    l_frag = {0.f, 0.f, 0.f, 0.f};
#pragma unroll
    for (int nf = 0; nf < 4; ++nf) o_acc[nf] = {0.f, 0.f, 0.f, 0.f};

    const int srow0 = t >> 3, sc8 = (t & 7) * 8;   // 32 rows x 8 cols per wave set
    const int srow1 = srow0 + 32;

    const unsigned short* kg0 = &qkb[qk_base + (size_t)srow0 * 2048 + 1024 + h * 64 + sc8];
    const unsigned short* kg1 = kg0 + (size_t)32 * 2048;
    const unsigned short* vg0 = &vbT[vt_base + (size_t)srow0 * 2048 + sc8];
    const unsigned short* vg1 = vg0 + (size_t)32 * 2048;

    u16x8 kr[2], vr[2];
    // tile 0 -> buf 0
    kr[0] = *reinterpret_cast<const u16x8*>(kg0);
    kr[1] = *reinterpret_cast<const u16x8*>(kg1);
    vr[0] = *reinterpret_cast<const u16x8*>(vg0);
    vr[1] = *reinterpret_cast<const u16x8*>(vg1);
    *reinterpret_cast<u16x8*>(&Ks[0][srow0][sc8]) = kr[0];
    *reinterpret_cast<u16x8*>(&Ks[0][srow1][sc8]) = kr[1];
    *reinterpret_cast<u16x8*>(&Vt[0][srow0][sc8]) = vr[0];
    *reinterpret_cast<u16x8*>(&Vt[0][srow1][sc8]) = vr[1];
    // tile 1 -> regs
    kr[0] = *reinterpret_cast<const u16x8*>(kg0 + (size_t)64 * 2048);
    kr[1] = *reinterpret_cast<const u16x8*>(kg1 + (size_t)64 * 2048);
    vr[0] = *reinterpret_cast<const u16x8*>(vg0 + 64);
    vr[1] = *reinterpret_cast<const u16x8*>(vg1 + 64);
    __syncthreads();

    for (int it = 0; it < 32; ++it) {
        const int cur = it & 1, nxt = cur ^ 1;
        // stage tile it+1 into the other buffer (reads of it were fenced by
        // the barrier at the end of iter it-1)
        if (it + 1 < 32) {
            *reinterpret_cast<u16x8*>(&Ks[nxt][srow0][sc8]) = kr[0];
            *reinterpret_cast<u16x8*>(&Ks[nxt][srow1][sc8]) = kr[1];
            *reinterpret_cast<u16x8*>(&Vt[nxt][srow0][sc8]) = vr[0];
            *reinterpret_cast<u16x8*>(&Vt[nxt][srow1][sc8]) = vr[1];
        }
        // prefetch tile it+2 from global (latency hidden under this iter)
        if (it + 2 < 32) {
            const size_t ko = (size_t)(it + 2) * 64 * 2048;
            const int vo = (it + 2) * 64;
            kr[0] = *reinterpret_cast<const u16x8*>(kg0 + ko);
            kr[1] = *reinterpret_cast<const u16x8*>(kg1 + ko);
            vr[0] = *reinterpret_cast<const u16x8*>(vg0 + vo);
            vr[1] = *reinterpret_cast<const u16x8*>(vg1 + vo);
        }

#pragma unroll
        for (int kh = 0; kh < 2; ++kh) {
            // S^T for the two 16-key fragments of this 32-key half
            unsigned d0[2], d1[2];   // [kfi]
#pragma unroll
            for (int kfi = 0; kfi < 2; ++kfi) {
                const int kf = kh * 2 + kfi;
                bf16x8 kfr0 = __builtin_bit_cast(bf16x8,
                    *reinterpret_cast<const u16x8*>(&Ks[cur][kf * 16 + l16][quad * 8]));
                bf16x8 kfr1 = __builtin_bit_cast(bf16x8,
                    *reinterpret_cast<const u16x8*>(&Ks[cur][kf * 16 + l16][32 + quad * 8]));
                f32x4 s = {0.f, 0.f, 0.f, 0.f};
                s = __builtin_amdgcn_mfma_f32_16x16x32_bf16(kfr0, qf[0], s, 0, 0, 0);
                s = __builtin_amdgcn_mfma_f32_16x16x32_bf16(kfr1, qf[1], s, 0, 0, 0);
                d0[kfi] = (unsigned)f2b(exp2f(s[0])) |
                          ((unsigned)f2b(exp2f(s[1])) << 16);
                d1[kfi] = (unsigned)f2b(exp2f(s[2])) |
                          ((unsigned)f2b(exp2f(s[3])) << 16);
            }
            // in-register transpose to PV A-frag: lane keeps its q (=l16),
            // keys redistributed across quads via the two swap ops.
            unsigned x0 = d0[0], y0 = d0[1];
            unsigned x1 = d1[0], y1 = d1[1];
            asm("v_permlane32_swap_b32 %0, %1\n\t"
                "v_permlane16_swap_b32 %0, %1"
                : "+v"(x0), "+v"(y0));
            asm("v_permlane32_swap_b32 %0, %1\n\t"
                "v_permlane16_swap_b32 %0, %1"
                : "+v"(x1), "+v"(y1));
            u32x4 pw = {x0, x1, y0, y1};   // W0,W1,W2,W3
            bf16x8 pfr = __builtin_bit_cast(bf16x8, pw);
            l_frag = __builtin_amdgcn_mfma_f32_16x16x32_bf16(
                pfr, onesf, l_frag, 0, 0, 0);
            __builtin_amdgcn_s_setprio(1);
#pragma unroll
            for (int nf = 0; nf < 4; ++nf) {
                bf16x8 vfr = __builtin_bit_cast(bf16x8,
                    *reinterpret_cast<const u16x8*>(&Vt[cur][nf * 16 + l16][kh * 32 + quad * 8]));
                o_acc[nf] = __builtin_amdgcn_mfma_f32_16x16x32_bf16(
                    pfr, vfr, o_acc[nf], 0, 0, 0);
            }
            __builtin_amdgcn_s_setprio(0);
        }
        __syncthreads();
    }

    // store: o_acc rows q = q0 + quad*4 + r; l_frag rows align.
#pragma unroll
    for (int r = 0; r < 4; ++r) {
        const float inv = 1.0f / l_frag[r];
        const int row = q0 + quad * 4 + r;
#pragma unroll
        for (int nf = 0; nf < 4; ++nf)
            ao[(size_t)b * 2048 * 1024 + (size_t)row * 1024 + h * 64 + nf * 16 + l16] =
                f2b(o_acc[nf][r] * inv);
    }
}

// ---------------------------------------------------------------------------
extern "C" void kernel_launch(void* const* d_in, const int* in_sizes, int n_in,
                              void* d_out, int out_size, void* d_ws, size_t ws_size,
                              hipStream_t stream)
{
    const float* x   = (const float*)d_in[0];
    const float* wq  = (const float*)d_in[1];
    const float* bq  = (const float*)d_in[2];
    const float* wk  = (const float*)d_in[3];
    const float* bk  = (const float*)d_in[4];
    const float* wv  = (const float*)d_in[5];
    const float* bv  = (const float*)d_in[6];
    const float* wo  = (const float*)d_in[7];
    const float* bo  = (const float*)d_in[8];
    const float* w1  = (const float*)d_in[9];
    const float* b1  = (const float*)d_in[10];
    const float* w2  = (const float*)d_in[11];
    const float* b2  = (const float*)d_in[12];
    const float* g1  = (const float*)d_in[13];
    const float* be1 = (const float*)d_in[14];
    const float* g2  = (const float*)d_in[15];
    const float* be2 = (const float*)d_in[16];
    float* out = (float*)d_out;
    char*  ws  = (char*)d_ws;

    const int M = 4096, D = 1024, DFF = 4096;
    const size_t MB = 1 << 20;

    unsigned short* wqkvT = (unsigned short*)(ws + 0 * MB);   // [3072][1024] 6MB
    unsigned short* woT   = (unsigned short*)(ws + 6 * MB);   // 2MB
    unsigned short* w1T   = (unsigned short*)(ws + 8 * MB);   // 8MB
    unsigned short* w2T   = (unsigned short*)(ws + 16 * MB);  // 8MB
    unsigned short* ln    = (unsigned short*)(ws + 24 * MB);  // 8MB
    unsigned short* qkb   = (unsigned short*)(ws + 32 * MB);  // 16MB
    unsigned short* vbT   = (unsigned short*)(ws + 48 * MB);  // 8MB
    unsigned short* ao    = (unsigned short*)(ws + 56 * MB);  // 8MB
    unsigned short* ff1   = (unsigned short*)(ws + 32 * MB);  // 32MB (reuse)
    float*          x2    = (float*)(ws + 64 * MB);           // 16MB
    float*          bqkv  = (float*)(ws + 80 * MB);           // 12KB (pre-partials)
    unsigned short* pHi   = (unsigned short*)(ws + 80 * MB);  // slices 0,1 (16MB)
    unsigned short* pOlo  = (unsigned short*)(ws + 32 * MB);  // O-proj slices 2,3
    unsigned short* pFlo  = (unsigned short*)(ws + 0 * MB);   // FF2 slices 2,3

    // --- weight prep + LN1 ---
    transpose_all_k<<<12288, 256, 0, stream>>>(wq, wk, wv, wo, w1, w2,
                                               wqkvT, woT, w1T, w2T);
    concat3_k<<<12, 256, 0, stream>>>(bq, bk, bv, bqkv);
    ln_kernel<<<M, 256, 0, stream>>>(x, g1, be1, ln);
    // --- fused QKV projection: QK' -> qkb, V -> vbT (V^T) ---
    gemm_bt<2, 0><<<dim3(24, 32), 256, 0, stream>>>(
        ln, D, wqkvT, D, bqkv, qkb, vbT, 3072, D);
    // --- attention ---
    attn_kernel<<<dim3(32, 32), 256, 0, stream>>>(qkb, vbT, ao);
    // --- O projection split-K4 bf16 partials; reduce + residual + LN2 ---
    gemm_bt<5, 0><<<dim3(8, 32, 4), 256, 0, stream>>>(
        ao, D, woT, D, nullptr, pHi, pOlo, 1024, 256);
    reduce_ln_kernel<<<M, 256, 0, stream>>>(pHi, pOlo, bo, x, g2, be2, x2, ln);
    // --- FFN ---
    gemm_bt<0, 1><<<dim3(32, 32), 256, 0, stream>>>(
        ln, D, w1T, D, b1, ff1, nullptr, DFF, D);
    gemm_bt<5, 0><<<dim3(8, 32, 4), 256, 0, stream>>>(
        ff1, DFF, w2T, DFF, nullptr, pHi, pFlo, 1024, 1024);
    reduce_out4_k<<<4096, 256, 0, stream>>>(pHi, pFlo, b2, x2, out);
}